// Round 2
// baseline (180.188 us; speedup 1.0000x reference)
//
#include <hip/hip_runtime.h>

// Segmented CRF forward (OneCrfCCKSDecoder), exp-domain formulation. R2.
// T=128, B=512, E=128, EVENTLEN=8, NEG=-10000.
//
// R2 layout: 512 wgs x 128 threads; ONE batch per wg, lane owns j = tid.
// vs R1 (2 batches / 256-thr wg): halves per-batch LDS broadcast reads
// (each h vector read by 2 waves instead of 4) and halves barrier width.
// exp(T[j,:]) register/AGPR-resident (128 regs); exp(feat) precomputed one
// step ahead (off the u->h->dot critical path); feats prefetched 3 deep.
//
// Per batch: state fv[j] = M + log u[j].
// Update step t (t%8!=0): u_new[j] = sum_k (u[k]*exp(feat[t,b,k])) * exp(T[j,k])
// Renorm by row max every 4 steps (t%4==3 produce via wave butterfly + LDS,
// t%4==0 consume after barrier). Worst-case 4-step growth e^~55 << fp32 max.
// Boundary t%8==0 (t>0) and terminal: alpha += M + log(sum_j u[j]*exp(T[127,j])).
// Output = sum_b alpha_b / (512*16).

#define NEG_VAL (-10000.0f)

__global__ __launch_bounds__(128, 1)
void crf_fwd(const float* __restrict__ feats,   // [128][512][128]
             const float* __restrict__ trans,   // [128][128]
             float* __restrict__ out)
{
    const int tid = threadIdx.x;   // 0..127
    const int j   = tid;           // owned entity index
    const int wav = tid >> 6;      // wave id 0..1
    const int b   = blockIdx.x;    // one batch per wg

    // exp of transitions row j (dot B-operand), register/AGPR resident.
    float Breg[128];
    #pragma unroll
    for (int k = 0; k < 128; k += 4) {
        float4 tv = *(const float4*)(trans + j * 128 + k);
        Breg[k + 0] = __expf(tv.x);
        Breg[k + 1] = __expf(tv.y);
        Breg[k + 2] = __expf(tv.z);
        Breg[k + 3] = __expf(tv.w);
    }
    const float te = __expf(trans[127 * 128 + j]);  // exp(T[E-1, j])

    __shared__ float h_lds[2][128];  // double-buffered h
    __shared__ float wmax[2];        // per-wave renorm max partials
    __shared__ float wsum[2];        // per-wave boundary sum partials

    // feat element for step t lives at fb[t * 65536]
    const float* fb = feats + (size_t)b * 128 + j;
    // software pipeline: ef_cur = exp(feat[t]), ef_next = exp(feat[t+1]),
    // f_next = raw feat[t+2] (loads 3 ahead of use, exp 1 ahead).
    float ef_cur  = __expf(fb[1 * 65536]);
    float ef_next = __expf(fb[2 * 65536]);
    float f_next  = fb[3 * 65536];

    float u     = 1.0f;
    float M     = (b == 0) ? 0.0f : NEG_VAL;  // init_fv zeroes only batch-0 row
    float alpha = 0.0f;

    for (int t = 1; t < 128; ++t) {
        float ef = ef_cur;               // exp(feat[t]) — ready, off chain
        ef_cur = ef_next;
        ef_next = __expf(f_next);
        f_next = (t + 4 < 128) ? fb[(size_t)(t + 4) * 65536] : 0.0f;

        if ((t & 3) == 0) {
            // consume renorm produced at t-1 (t-1 % 4 == 3)
            __syncthreads();
            float c = fmaxf(wmax[0], wmax[1]);
            u = u / c;
            M += __logf(c);              // wg-uniform
        }

        if ((t & 7) != 0) {
            // ---- DP update ----
            h_lds[t & 1][j] = u * ef;
            __syncthreads();

            const float4* hv = (const float4*)h_lds[t & 1];
            float s0 = 0.f, s1 = 0.f, s2 = 0.f, s3 = 0.f;
            #pragma unroll
            for (int i = 0; i < 32; ++i) {
                float4 v = hv[i];        // wave-uniform broadcast read
                s0 = fmaf(Breg[4 * i + 0], v.x, s0);
                s1 = fmaf(Breg[4 * i + 1], v.y, s1);
                s2 = fmaf(Breg[4 * i + 2], v.z, s2);
                s3 = fmaf(Breg[4 * i + 3], v.w, s3);
            }
            u = (s0 + s1) + (s2 + s3);

            if ((t & 3) == 3) {
                // produce renorm partial: butterfly max over wave
                float m = u;
                #pragma unroll
                for (int off = 1; off < 64; off <<= 1)
                    m = fmaxf(m, __shfl_xor(m, off, 64));
                if ((tid & 63) == 0) wmax[wav] = m;
                // visible after the consume barrier at t+1
            }
        } else {
            // ---- event boundary: alpha accumulation (fv unchanged) ----
            float r = u * te;
            #pragma unroll
            for (int off = 1; off < 64; off <<= 1)
                r += __shfl_xor(r, off, 64);
            if ((tid & 63) == 0) wsum[wav] = r;
            __syncthreads();
            alpha += M + __logf(wsum[0] + wsum[1]);  // wg-uniform
        }
    }

    // consume pending renorm from t=127 (127 % 4 == 3)
    __syncthreads();
    {
        float c = fmaxf(wmax[0], wmax[1]);
        u = u / c;
        M += __logf(c);
    }
    // terminal accumulation
    {
        float r = u * te;
        #pragma unroll
        for (int off = 1; off < 64; off <<= 1)
            r += __shfl_xor(r, off, 64);
        if ((tid & 63) == 0) wsum[wav] = r;
        __syncthreads();
        alpha += M + __logf(wsum[0] + wsum[1]);
    }

    if (tid == 0)
        atomicAdd(out, alpha * (1.0f / (512.0f * 16.0f)));
}

extern "C" void kernel_launch(void* const* d_in, const int* in_sizes, int n_in,
                              void* d_out, int out_size, void* d_ws, size_t ws_size,
                              hipStream_t stream) {
    const float* feats = (const float*)d_in[0];   // [128,512,128] f32
    const float* trans = (const float*)d_in[1];   // [128,128] f32
    float* out = (float*)d_out;                   // scalar f32

    hipMemsetAsync(out, 0, sizeof(float), stream);
    crf_fwd<<<512, 128, 0, stream>>>(feats, trans, out);
}

// Round 3
// 167.340 us; speedup vs baseline: 1.0768x; 1.0768x over previous
//
#include <hip/hip_runtime.h>

// Segmented CRF forward (OneCrfCCKSDecoder), exp-domain, R3.
// T=128, B=512, E=128, EVENTLEN=8, NEG=-10000.
//
// R1/R2 post-mortem: both ran 115-118us = (128 ds_read_b128 per CU per step)
// x 12cyc -> LDS-pipe-throughput bound on the h broadcast reads. R3 cuts the
// read count 4x: (a) 1 wave per batch, lane owns rows j=2L,2L+1 (E rows in
// VGPRs, 2 rows reuse each broadcast), (b) h packed f16 -> 16 b128 reads per
// step, dot via v_dot2_f32_f16 (f32 accumulate).
//
// Numerics: state fv[j] = M + log u[j]; renorm u by wave-max EVERY update
// step => u<=1, h = u*exp(feat) <= ~250 (f16-safe). Threshold is 192 abs;
// f16 mantissa error ~1e-2 final. Row0 / col127 of exp(T) are exactly 0,
// matching fp32 exp(-10000)=0 in the reference.
//
// wg = 64 threads (one wave): s_barrier elided by the compiler for
// flat-work-group-size <= wavesize, so prefetched global loads are never
// drained by a barrier. Global feat loads float2, 3 steps ahead.

typedef _Float16 h2_t __attribute__((ext_vector_type(2)));
typedef _Float16 h8_t __attribute__((ext_vector_type(8)));

#define NEG_VAL (-10000.0f)

#if __has_builtin(__builtin_amdgcn_fdot2)
#define FDOT2(a, b, c) __builtin_amdgcn_fdot2((a), (b), (c), false)
#else
static __device__ __forceinline__ float FDOT2(h2_t a, h2_t b, float c) {
    return c + (float)a[0] * (float)b[0] + (float)a[1] * (float)b[1];
}
#endif

__global__ __launch_bounds__(64)
void crf_fwd(const float* __restrict__ feats,   // [128][512][128]
             const float* __restrict__ trans,   // [128][128]
             float* __restrict__ out)
{
    const int L  = threadIdx.x;     // 0..63
    const int b  = blockIdx.x;      // one batch per wave
    const int j0 = 2 * L;
    const int j1 = 2 * L + 1;

    // E rows j0, j1 = exp(trans row), f16-packed over k. 128 VGPRs total.
    h2_t E0[64], E1[64];
    {
        const float4* r0 = (const float4*)(trans + (size_t)j0 * 128);
        const float4* r1 = (const float4*)(trans + (size_t)j1 * 128);
        #pragma unroll
        for (int i = 0; i < 32; ++i) {
            float4 a = r0[i];
            float4 c = r1[i];
            h2_t p;
            p[0] = (_Float16)__expf(a.x); p[1] = (_Float16)__expf(a.y); E0[2*i]   = p;
            p[0] = (_Float16)__expf(a.z); p[1] = (_Float16)__expf(a.w); E0[2*i+1] = p;
            p[0] = (_Float16)__expf(c.x); p[1] = (_Float16)__expf(c.y); E1[2*i]   = p;
            p[0] = (_Float16)__expf(c.z); p[1] = (_Float16)__expf(c.w); E1[2*i+1] = p;
        }
    }
    const float te0 = __expf(trans[127 * 128 + j0]);  // exp(T[E-1, j0])
    const float te1 = __expf(trans[127 * 128 + j1]);

    __shared__ __align__(16) h2_t hbuf[64];   // packed h: pair (2L, 2L+1) at [L]

    // feat pair [t][b][2L..2L+1]; per-t stride = 65536 floats = 32768 float2
    const float2* fb = (const float2*)(feats + (size_t)b * 128 + 2 * L);
    #define FSTR 32768

    // pipeline: ef = exp(feat[t]); fA = raw feat[t+1]; fB = raw feat[t+2]
    float2 l1 = fb[1 * FSTR];
    float2 fA = fb[2 * FSTR];
    float2 fB = fb[3 * FSTR];
    float ef0 = __expf(l1.x), ef1 = __expf(l1.y);

    float u0 = 1.0f, u1 = 1.0f;
    float M     = (b == 0) ? 0.0f : NEG_VAL;  // init_fv zeroes only batch-0 row
    float alpha = 0.0f;

    for (int t = 1; t < 128; ++t) {
        const bool upd = (t & 7) != 0;

        if (upd) {
            // publish h = u * exp(feat[t]) as packed f16 (u<=1 -> h<=~250)
            h2_t hh;
            hh[0] = (_Float16)(u0 * ef0);
            hh[1] = (_Float16)(u1 * ef1);
            __syncthreads();            // elided to wave fence (wg == wave)
            hbuf[L] = hh;
            __syncthreads();
        }

        // rotate feat pipeline (loads issued far from any use)
        float2 nf;
        nf.x = 0.0f; nf.y = 0.0f;
        if (t + 3 < 128) nf = fb[(size_t)(t + 3) * FSTR];
        const float efn0 = __expf(fA.x), efn1 = __expf(fA.y);  // for t+1
        fA = fB; fB = nf;

        if (upd) {
            // ---- DP update: u_new[j] = sum_k h[k] * E[j,k] ----
            const h8_t* hv = (const h8_t*)hbuf;
            float a0 = 0.f, b0 = 0.f;   // two chains for j0
            float a1 = 0.f, b1 = 0.f;   // two chains for j1
            #pragma unroll
            for (int i = 0; i < 16; ++i) {
                h8_t v = hv[i];         // wave-uniform broadcast, 8 h values
                h2_t p0; p0[0] = v[0]; p0[1] = v[1];
                h2_t p1; p1[0] = v[2]; p1[1] = v[3];
                h2_t p2; p2[0] = v[4]; p2[1] = v[5];
                h2_t p3; p3[0] = v[6]; p3[1] = v[7];
                a0 = FDOT2(E0[4*i + 0], p0, a0);
                b0 = FDOT2(E0[4*i + 1], p1, b0);
                a0 = FDOT2(E0[4*i + 2], p2, a0);
                b0 = FDOT2(E0[4*i + 3], p3, b0);
                a1 = FDOT2(E1[4*i + 0], p0, a1);
                b1 = FDOT2(E1[4*i + 1], p1, b1);
                a1 = FDOT2(E1[4*i + 2], p2, a1);
                b1 = FDOT2(E1[4*i + 3], p3, b1);
            }
            float s0 = a0 + b0;
            float s1 = a1 + b1;

            // renorm every step: c = max_j u_new (wave butterfly), u /= c
            float c = fmaxf(s0, s1);
            #pragma unroll
            for (int off = 1; off < 64; off <<= 1)
                c = fmaxf(c, __shfl_xor(c, off, 64));
            const float inv = __builtin_amdgcn_rcpf(c);
            u0 = s0 * inv;
            u1 = s1 * inv;
            M += __logf(c);
        } else {
            // ---- event boundary: alpha += M + log(sum_j u[j]*exp(T[127,j]))
            float r = u0 * te0 + u1 * te1;
            #pragma unroll
            for (int off = 1; off < 64; off <<= 1)
                r += __shfl_xor(r, off, 64);
            alpha += M + __logf(r);     // wave-uniform
        }

        ef0 = efn0; ef1 = efn1;
    }

    // terminal accumulation
    {
        float r = u0 * te0 + u1 * te1;
        #pragma unroll
        for (int off = 1; off < 64; off <<= 1)
            r += __shfl_xor(r, off, 64);
        alpha += M + __logf(r);
    }

    if (L == 0)
        atomicAdd(out, alpha * (1.0f / (512.0f * 16.0f)));
}

extern "C" void kernel_launch(void* const* d_in, const int* in_sizes, int n_in,
                              void* d_out, int out_size, void* d_ws, size_t ws_size,
                              hipStream_t stream) {
    const float* feats = (const float*)d_in[0];   // [128,512,128] f32
    const float* trans = (const float*)d_in[1];   // [128,128] f32
    float* out = (float*)d_out;                   // scalar f32

    hipMemsetAsync(out, 0, sizeof(float), stream);
    crf_fwd<<<512, 64, 0, stream>>>(feats, trans, out);
}